// Round 3
// baseline (688.861 us; speedup 1.0000x reference)
//
#include <hip/hip_runtime.h>
#include <hip/hip_bf16.h>
#include <math.h>

// ---------------------------------------------------------------------------
// MoGCN: two 2-layer GCN branches (H=64) + concat + FC(128->4), fp32 in/out.
// Round 8: gemm_l1 occupancy/VALU rebalance.
//   R7 post-mortem: 64 rows/wave collapsed occupancy 68->18.5% (VGPR 108,
//   3 blocks/CU) and the manual f2bf_rne split-pack chain (~17 VALU/pair)
//   dominated issue. Now: 32 rows/wave (grid 2x, VGPR ~90) and RNE pair
//   conversion via __float22bfloat162_rn -> v_cvt_pk_bf16_f32 (~6 VALU/pair,
//   numerically identical). Everything else unchanged (verified).
// ---------------------------------------------------------------------------

#define H 64
#define BCAP 16384            // per-bucket capacity (avg fill ~4096, +190 sigma)

static inline int ceil_div(int a, int b) { return (a + b - 1) / b; }

typedef __attribute__((ext_vector_type(8))) short short8_t;  // 8 bf16
typedef __attribute__((ext_vector_type(4))) float f32x4;

__device__ inline unsigned short f2bf_rne(float f) {
    unsigned u = __float_as_uint(f);
    u += 0x7fffu + ((u >> 16) & 1u);
    return (unsigned short)(u >> 16);
}
__device__ inline unsigned pk_bf(float a, float b) {
    return (unsigned)f2bf_rne(a) | ((unsigned)f2bf_rne(b) << 16);
}
__device__ inline float2 bf2x(unsigned w) {
    float2 r;
    r.x = __uint_as_float(w << 16);
    r.y = __uint_as_float(w & 0xffff0000u);
    return r;
}
union V8 { uint4 u4; unsigned u[4]; short8_t s; };

// RNE split-pack: (a,b) -> hi bf16x2 (packed) + lo bf16x2 (packed residual).
// Uses v_cvt_pk_bf16_f32 via __float22bfloat162_rn (same RNE as f2bf_rne).
__device__ inline void split_pack2(float a, float b, unsigned& hi, unsigned& lo) {
    union { __hip_bfloat162 h; unsigned u; } hp, lp;
    hp.h = __float22bfloat162_rn(make_float2(a, b));
    float fa = __uint_as_float(hp.u << 16);
    float fb = __uint_as_float(hp.u & 0xffff0000u);
    lp.h = __float22bfloat162_rn(make_float2(a - fa, b - fb));
    hi = hp.u;
    lo = lp.u;
}

// ---- pass 1: bucket edges by dst>>8 (packed src | dlocal<<17) -------------
// 2048 edges/block; LDS histogram; one cursor atomic per (block,bucket).
__global__ __launch_bounds__(256) void bucket_scatter_kernel(
        const int* __restrict__ src, const int* __restrict__ dst,
        int* __restrict__ cursor, unsigned* __restrict__ bucketed,
        int E, int nbkt) {
    __shared__ int lcnt[512];
    __shared__ int lbase[512];
    const int t = threadIdx.x;
    for (int b = t; b < nbkt; b += 256) lcnt[b] = 0;
    __syncthreads();

    unsigned val[8];
    int bkt[8], lpos[8];
    const int e0 = blockIdx.x * 2048;
#pragma unroll
    for (int k = 0; k < 8; ++k) {
        int e = e0 + k * 256 + t;
        bkt[k] = -1;
        if (e < E) {
            int s = src[e];
            int d = dst[e];
            int b = d >> 8;
            val[k] = (unsigned)s | ((unsigned)(d & 255) << 17);
            bkt[k] = b;
            lpos[k] = atomicAdd(&lcnt[b], 1);
        }
    }
    __syncthreads();
    for (int b = t; b < nbkt; b += 256) {
        int c = lcnt[b];
        lbase[b] = c > 0 ? atomicAdd(&cursor[b], c) : 0;
    }
    __syncthreads();
#pragma unroll
    for (int k = 0; k < 8; ++k) {
        if (bkt[k] >= 0) {
            int p = lbase[bkt[k]] + lpos[k];
            if (p < BCAP)  // impossible overflow guard (keeps writes in range)
                bucketed[(size_t)bkt[k] * BCAP + p] = val[k];
        }
    }
}

// ---- pass 2: per-bucket exact CSR + row_ptr + dinv ------------------------
// one block per bucket (256 dst nodes, ~4K edges). Dense coalesced IO.
// Block computes its own exclusive prefix over cursor[0..b) (replaces the
// standalone scan kernel: <=391 int reads + tree reduce, negligible).
__global__ __launch_bounds__(256) void bucket_csr_kernel(
        const unsigned* __restrict__ bucketed, const int* __restrict__ cursor,
        int* __restrict__ csr_src, int* __restrict__ row_ptr,
        float* __restrict__ dinv, int N, int E) {
    __shared__ int dcnt[256];
    __shared__ int dbase[256];
    __shared__ int dcur[256];
    const int t = threadIdx.x;
    const int b = blockIdx.x;

    // inline exclusive prefix: base = sum(cursor[0..b-1])
    int part = 0;
    for (int i = t; i < b; i += 256) part += cursor[i];
    dbase[t] = part;
    __syncthreads();
#pragma unroll
    for (int off = 128; off > 0; off >>= 1) {
        if (t < off) dbase[t] += dbase[t + off];
        __syncthreads();
    }
    const int base = dbase[0];
    const int cnt = min(cursor[b], BCAP);
    const unsigned* bed = bucketed + (size_t)b * BCAP;
    if (b == 0 && t == 0) row_ptr[N] = E;

    dcnt[t] = 0;
    __syncthreads();               // also fences the dbase[0] reads above
    for (int i = t; i < cnt; i += 256) {
        unsigned v = bed[i];
        atomicAdd(&dcnt[v >> 17], 1);
    }
    __syncthreads();
    int myc = dcnt[t];
    // exclusive scan over 256 (Hillis-Steele, in place)
    int acc = myc;
    dbase[t] = acc;
    __syncthreads();
#pragma unroll
    for (int off = 1; off < 256; off <<= 1) {
        int u = (t >= off) ? dbase[t - off] : 0;
        __syncthreads();
        dbase[t] += u;
        __syncthreads();
    }
    int excl = dbase[t] - myc;
    dcur[t] = excl;
    int node = b * 256 + t;
    if (node < N) {
        row_ptr[node] = base + excl;
        dinv[node] = rsqrtf((float)myc + 1.0f);  // +1 self loop
    }
    __syncthreads();
    for (int i = t; i < cnt; i += 256) {
        unsigned v = bed[i];
        int dl = v >> 17;
        int p = atomicAdd(&dcur[dl], 1);
        csr_src[base + p] = (int)(v & 0x1FFFFu);
    }
}

// ---- W fragment pre-pack, all four weights in ONE launch ------------------
// W[K][64] fp32 -> hi/lo bf16 MFMA lane order.
// Segments (exact fits): Wa K=512 -> 16 blocks, Wb K=256 -> 8, Wc/Wd K=64 -> 2+2.
// Block 0 additionally zeroes the 512-entry bucket cursor array (replaces
// the hipMemsetAsync dispatch; this kernel is enqueued before the scatter).
__global__ __launch_bounds__(256) void wfrag4_kernel(
        const float* __restrict__ Wa, uint4* __restrict__ fa,
        const float* __restrict__ Wb, uint4* __restrict__ fb,
        const float* __restrict__ Wc, uint4* __restrict__ fc,
        const float* __restrict__ Wd, uint4* __restrict__ fd,
        int* __restrict__ cursor) {
    const int bid = blockIdx.x;
    if (bid == 0) {
        cursor[threadIdx.x] = 0;
        cursor[threadIdx.x + 256] = 0;
    }
    const float* W;
    uint4* frag;
    int K, t;
    if (bid < 16)      { W = Wa; frag = fa; K = 512; t = bid * 256 + threadIdx.x; }
    else if (bid < 24) { W = Wb; frag = fb; K = 256; t = (bid - 16) * 256 + threadIdx.x; }
    else if (bid < 26) { W = Wc; frag = fc; K = 64;  t = (bid - 24) * 256 + threadIdx.x; }
    else               { W = Wd; frag = fd; K = 64;  t = (bid - 26) * 256 + threadIdx.x; }
    int total = (K >> 5) * 256;
    if (t >= total) return;
    int lane = t & 63, nt = (t >> 6) & 3, ks = t >> 8;
    int nl = lane & 15, q = lane >> 4;
    float hi[8], lo[8];
#pragma unroll
    for (int j = 0; j < 8; ++j) {
        float w = W[(size_t)(ks * 32 + q * 8 + j) * 64 + nt * 16 + nl];
        unsigned hb = f2bf_rne(w);
        float hf = __uint_as_float(((unsigned)hb) << 16);
        hi[j] = hf;
        lo[j] = w - hf;
    }
    V8 vh, vl;
#pragma unroll
    for (int j = 0; j < 4; ++j) {
        vh.u[j] = pk_bf(hi[2 * j], hi[2 * j + 1]);
        vl.u[j] = pk_bf(lo[2 * j], lo[2 * j + 1]);
    }
    size_t base = (size_t)((ks * 4 + nt) * 2) * 64 + lane;
    frag[base] = vh.u4;
    frag[base + 64] = vl.u4;
}

// ---- layer-1 GEMM, both branches in one launch, 32 rows/wave --------------
// Hout_bf16[M,64] = X_fp32[M,K] @ W (bf16x3 split). Branch by blockIdx.
// Each wave: 2x 16-row subtiles sharing one wf-fragment fetch per K-step.
// 128 rows/block -> 1564 blocks (~6/CU) restores TLP lost in R7.
__global__ __launch_bounds__(256) void gemm_l1_kernel(
        const float* __restrict__ XA, const uint4* __restrict__ wfA,
        unsigned* __restrict__ HA, int KA,
        const float* __restrict__ XB, const uint4* __restrict__ wfB,
        unsigned* __restrict__ HB, int KB,
        int M, int nblkA) {
    const float* X;
    const uint4* wf;
    unsigned* Hout;
    int K, blk;
    if ((int)blockIdx.x < nblkA) { X = XA; wf = wfA; Hout = HA; K = KA; blk = blockIdx.x; }
    else                         { X = XB; wf = wfB; Hout = HB; K = KB; blk = blockIdx.x - nblkA; }

    const int tid = threadIdx.x;
    const int w = tid >> 6, l = tid & 63;
    const int m = l & 15, q = l >> 4;
    const int wbase = blk * 128 + w * 32;   // wave's 32-row region

    const float* Xr[2];
#pragma unroll
    for (int s = 0; s < 2; ++s) {
        int row = wbase + s * 16 + m;
        int rowc = row < M ? row : M - 1;
        Xr[s] = X + (size_t)rowc * K;
    }

    f32x4 acc[2][4];
#pragma unroll
    for (int s = 0; s < 2; ++s)
#pragma unroll
        for (int nt = 0; nt < 4; ++nt) acc[s][nt] = (f32x4){0.f, 0.f, 0.f, 0.f};

    const int ksteps = K >> 5;
    for (int ks = 0; ks < ksteps; ++ks) {
        // issue all X loads (4 independent) ...
        float4 xf[2][2];
#pragma unroll
        for (int s = 0; s < 2; ++s) {
            xf[s][0] = *(const float4*)&Xr[s][ks * 32 + q * 8];
            xf[s][1] = *(const float4*)&Xr[s][ks * 32 + q * 8 + 4];
        }
        // ... and all wf loads (8 independent, shared by both subtiles)
        const uint4* base = wf + (size_t)(ks * 4) * 2 * 64 + l;
        uint4 bh[4], bl[4];
#pragma unroll
        for (int nt = 0; nt < 4; ++nt) {
            bh[nt] = base[(size_t)(nt * 2) * 64];
            bl[nt] = base[(size_t)(nt * 2 + 1) * 64];
        }
#pragma unroll
        for (int s = 0; s < 2; ++s) {
            float xs[8] = {xf[s][0].x, xf[s][0].y, xf[s][0].z, xf[s][0].w,
                           xf[s][1].x, xf[s][1].y, xf[s][1].z, xf[s][1].w};
            V8 ah, al;
#pragma unroll
            for (int j = 0; j < 4; ++j)
                split_pack2(xs[2 * j], xs[2 * j + 1], ah.u[j], al.u[j]);
#pragma unroll
            for (int nt = 0; nt < 4; ++nt) {
                V8 vh, vl;
                vh.u4 = bh[nt];
                vl.u4 = bl[nt];
                acc[s][nt] = __builtin_amdgcn_mfma_f32_16x16x32_bf16(ah.s, vh.s, acc[s][nt], 0, 0, 0);
                acc[s][nt] = __builtin_amdgcn_mfma_f32_16x16x32_bf16(al.s, vh.s, acc[s][nt], 0, 0, 0);
                acc[s][nt] = __builtin_amdgcn_mfma_f32_16x16x32_bf16(ah.s, vl.s, acc[s][nt], 0, 0, 0);
            }
        }
    }

#pragma unroll
    for (int s = 0; s < 2; ++s) {
        const int rbase = wbase + s * 16 + q * 4;
#pragma unroll
        for (int nt = 0; nt < 4; ++nt) {
#pragma unroll
            for (int i = 0; i < 4; ++i) {
                float f = acc[s][nt][i];
                float fo = __shfl_xor(f, 1, 64);
                int r = rbase + i;
                if (((l & 1) == 0) && r < M)
                    Hout[(size_t)r * 32 + nt * 8 + (m >> 1)] = pk_bf(f, fo);
            }
        }
    }
}

// ---- layer-2 GEMM, both branches in one launch ----------------------------
// Hout_bf16[M,64] = X_bf16[M,64] @ W (W split, 2 MFMA).
__global__ __launch_bounds__(256) void gemm_l2_kernel(
        const uint4* __restrict__ XA, const uint4* __restrict__ wfA,
        unsigned* __restrict__ HA,
        const uint4* __restrict__ XB, const uint4* __restrict__ wfB,
        unsigned* __restrict__ HB,
        int M, int nblkA) {
    const uint4* Xb;
    const uint4* wf;
    unsigned* Hout;
    int blk;
    if ((int)blockIdx.x < nblkA) { Xb = XA; wf = wfA; Hout = HA; blk = blockIdx.x; }
    else                         { Xb = XB; wf = wfB; Hout = HB; blk = blockIdx.x - nblkA; }

    const int tid = threadIdx.x;
    const int w = tid >> 6, l = tid & 63;
    const int m = l & 15, q = l >> 4;
    const int tile = blk * 64 + w * 16;
    int row = tile + m;
    int rowc = row < M ? row : M - 1;

    f32x4 acc[4];
#pragma unroll
    for (int nt = 0; nt < 4; ++nt) acc[nt] = (f32x4){0.f, 0.f, 0.f, 0.f};

#pragma unroll
    for (int ks = 0; ks < 2; ++ks) {
        V8 av;
        av.u4 = Xb[(size_t)rowc * 8 + ks * 4 + q];
        const uint4* base = wf + (size_t)(ks * 4) * 2 * 64 + l;
#pragma unroll
        for (int nt = 0; nt < 4; ++nt) {
            V8 bh, bl;
            bh.u4 = base[(size_t)(nt * 2) * 64];
            bl.u4 = base[(size_t)(nt * 2 + 1) * 64];
            acc[nt] = __builtin_amdgcn_mfma_f32_16x16x32_bf16(av.s, bh.s, acc[nt], 0, 0, 0);
            acc[nt] = __builtin_amdgcn_mfma_f32_16x16x32_bf16(av.s, bl.s, acc[nt], 0, 0, 0);
        }
    }

    const int rbase = tile + q * 4;
#pragma unroll
    for (int nt = 0; nt < 4; ++nt) {
#pragma unroll
        for (int i = 0; i < 4; ++i) {
            float f = acc[nt][i];
            float fo = __shfl_xor(f, 1, 64);
            int r = rbase + i;
            if (((l & 1) == 0) && r < M)
                Hout[(size_t)r * 32 + nt * 8 + (m >> 1)] = pk_bf(f, fo);
        }
    }
}

// ---- fused dual-branch aggregation: selfloop+gather+bias+ELU [+FC] --------
// 2 dst nodes per wave; lane l holds features (2l,2l+1) as packed bf16.
// edge norm computed from the hot dinv table (no csr_norm stream).
__global__ __launch_bounds__(256) void agg2_kernel(const unsigned* __restrict__ h1,
                                                   const unsigned* __restrict__ h2,
                                                   const float* __restrict__ dinv,
                                                   const int* __restrict__ row_ptr,
                                                   const int* __restrict__ csr_src,
                                                   const float* __restrict__ b1,
                                                   const float* __restrict__ b2,
                                                   unsigned* __restrict__ o1,
                                                   unsigned* __restrict__ o2,
                                                   const float* __restrict__ Wfc,
                                                   const float* __restrict__ bfc,
                                                   float* __restrict__ out, int n) {
    const int tid  = threadIdx.x;
    const int lane = tid & 63;
    const int wave = tid >> 6;
    const int half = lane >> 5;
    const int l    = lane & 31;
    const int hb   = half << 5;
    const int node = blockIdx.x * 8 + wave * 2 + half;
    const bool active = (node < n);

    int r0 = 0, r1 = 0;
    float di = 0.f;
    if (active) { r0 = row_ptr[node]; r1 = row_ptr[node + 1]; di = dinv[node]; }
    const float di2 = di * di;
    const int rowoff = node * 32 + l;

    float2 acc1 = make_float2(0.f, 0.f), acc2 = make_float2(0.f, 0.f);
    if (active) {
        float2 s1 = bf2x(h1[rowoff]);
        float2 s2 = bf2x(h2[rowoff]);
        acc1.x = s1.x * di2; acc1.y = s1.y * di2;
        acc2.x = s2.x * di2; acc2.y = s2.y * di2;
    }

    for (int base = r0; base < r1; base += 32) {
        int cnt = r1 - base;
        if (cnt > 32) cnt = 32;
        int j = base + (l < cnt ? l : cnt - 1);   // coalesced chunk prefetch
        int sj = csr_src[j];
        float dsj = dinv[sj];                     // hot 400 KB table
#pragma unroll 4
        for (int t = 0; t < cnt; ++t) {
            int s    = __shfl(sj, hb | t, 64);
            float nr = __shfl(dsj, hb | t, 64) * di;
            float2 g1 = bf2x(h1[s * 32 + l]);
            float2 g2 = bf2x(h2[s * 32 + l]);
            acc1.x = fmaf(g1.x, nr, acc1.x);
            acc1.y = fmaf(g1.y, nr, acc1.y);
            acc2.x = fmaf(g2.x, nr, acc2.x);
            acc2.y = fmaf(g2.y, nr, acc2.y);
        }
    }

    float2 bv1 = ((const float2*)b1)[l];
    float2 bv2 = ((const float2*)b2)[l];
    float2 v1, v2;
    v1.x = acc1.x + bv1.x; v1.y = acc1.y + bv1.y;
    v2.x = acc2.x + bv2.x; v2.y = acc2.y + bv2.y;
    v1.x = v1.x > 0.f ? v1.x : (expf(v1.x) - 1.f);
    v1.y = v1.y > 0.f ? v1.y : (expf(v1.y) - 1.f);
    v2.x = v2.x > 0.f ? v2.x : (expf(v2.x) - 1.f);
    v2.y = v2.y > 0.f ? v2.y : (expf(v2.y) - 1.f);

    if (Wfc == nullptr) {
        if (active) {
            o1[rowoff] = pk_bf(v1.x, v1.y);
            o2[rowoff] = pk_bf(v2.x, v2.y);
        }
        return;
    }

    // fused FC head
    const float* Wp1 = &Wfc[(2 * l) * 4];
    const float* Wp2 = &Wfc[(H + 2 * l) * 4];
    float a[4];
#pragma unroll
    for (int c = 0; c < 4; ++c)
        a[c] = v1.x * Wp1[c] + v1.y * Wp1[4 + c] + v2.x * Wp2[c] + v2.y * Wp2[4 + c];
#pragma unroll
    for (int off = 16; off > 0; off >>= 1) {
#pragma unroll
        for (int c = 0; c < 4; ++c)
            a[c] += __shfl_down(a[c], off, 64);
    }
    if (l == 0 && active) {
#pragma unroll
        for (int c = 0; c < 4; ++c)
            out[(size_t)node * 4 + c] = a[c] + bfc[c];
    }
}

// ---------------------------------------------------------------------------
extern "C" void kernel_launch(void* const* d_in, const int* in_sizes, int n_in,
                              void* d_out, int out_size, void* d_ws, size_t ws_size,
                              hipStream_t stream) {
    const float* x_omic1 = (const float*)d_in[0];
    const float* x_omic2 = (const float*)d_in[1];
    const int*   eidx    = (const int*)d_in[2];
    const float* W1a = (const float*)d_in[3];
    const float* b1a = (const float*)d_in[4];
    const float* W2a = (const float*)d_in[5];
    const float* b2a = (const float*)d_in[6];
    const float* W1b = (const float*)d_in[7];
    const float* b1b = (const float*)d_in[8];
    const float* W2b = (const float*)d_in[9];
    const float* b2b = (const float*)d_in[10];
    const float* Wfc = (const float*)d_in[11];
    const float* bfc = (const float*)d_in[12];
    float* out = (float*)d_out;

    const int D1 = 512, D2 = 256;
    const int N = in_sizes[0] / D1;
    const int E = in_sizes[2] / 2;
    const int* src = eidx;
    const int* dst = eidx + E;
    const int nbkt = ceil_div(N, 256);   // 391 for N=100000 (must be <= 512)

    // workspace layout (4B units, 16B-aligned chunks)
    size_t off = 0;
    auto alloc = [&](size_t elems) { size_t o = off; off += (elems + 3) & ~(size_t)3; return o; };
    float*    base_f = (float*)d_ws;
    int*      base_i = (int*)d_ws;
    unsigned* base_u = (unsigned*)d_ws;
    float*    dinv     = base_f + alloc(N);
    int*      row_ptr  = base_i + alloc(N + 1);
    int*      cursor   = base_i + alloc(512);
    unsigned* bucketed = base_u + alloc((size_t)nbkt * BCAP);
    int*      csr_src  = base_i + alloc(E);
    unsigned* h1bf     = base_u + alloc((size_t)N * 32);  // N x 64 bf16
    unsigned* h2bf     = base_u + alloc((size_t)N * 32);
    unsigned* x1bf     = base_u + alloc((size_t)N * 32);
    unsigned* x2bf     = base_u + alloc((size_t)N * 32);
    uint4*    wf1a = (uint4*)(base_u + alloc((D1 / 32) * 2 * 256 * 4));
    uint4*    wf1b = (uint4*)(base_u + alloc((D2 / 32) * 2 * 256 * 4));
    uint4*    wf2a = (uint4*)(base_u + alloc((H  / 32) * 2 * 256 * 4));
    uint4*    wf2b = (uint4*)(base_u + alloc((H  / 32) * 2 * 256 * 4));

    dim3 blk(256);
    dim3 grid_agg(ceil_div(N, 8));
    const int nblk = ceil_div(N, 64);      // gemm_l2 tiling (64 rows/block)
    const int nblkL1 = ceil_div(N, 128);   // gemm_l1 tiling (128 rows/block)

    // 1) W pre-pack (all four) + cursor zeroing — must precede the scatter.
    wfrag4_kernel<<<28, blk, 0, stream>>>(W1a, wf1a, W1b, wf1b, W2a, wf2a,
                                          W2b, wf2b, cursor);
    // 2-3) CSR build (bucketed counting sort; scan inlined into pass 3).
    bucket_scatter_kernel<<<ceil_div(E, 2048), blk, 0, stream>>>(src, dst, cursor,
                                                                 bucketed, E, nbkt);
    bucket_csr_kernel<<<nbkt, blk, 0, stream>>>(bucketed, cursor, csr_src,
                                                row_ptr, dinv, N, E);
    // 4) layer 1, both branches, one launch (128 rows/block).
    gemm_l1_kernel<<<2 * nblkL1, blk, 0, stream>>>(x_omic1, wf1a, h1bf, D1,
                                                   x_omic2, wf1b, h2bf, D2, N, nblkL1);
    // 5) layer-1 aggregation + ELU.
    agg2_kernel<<<grid_agg, blk, 0, stream>>>(h1bf, h2bf, dinv, row_ptr, csr_src,
                                              b1a, b1b, x1bf, x2bf,
                                              nullptr, nullptr, nullptr, N);
    // 6) layer 2, both branches, one launch.
    gemm_l2_kernel<<<2 * nblk, blk, 0, stream>>>((const uint4*)x1bf, wf2a, h1bf,
                                                 (const uint4*)x2bf, wf2b, h2bf,
                                                 N, nblk);
    // 7) layer-2 aggregation + ELU + fused FC head.
    agg2_kernel<<<grid_agg, blk, 0, stream>>>(h1bf, h2bf, dinv, row_ptr, csr_src,
                                              b2a, b2b, nullptr, nullptr,
                                              Wfc, bfc, out, N);
}

// Round 4
// 681.578 us; speedup vs baseline: 1.0107x; 1.0107x over previous
//
#include <hip/hip_runtime.h>
#include <hip/hip_bf16.h>
#include <math.h>

// ---------------------------------------------------------------------------
// MoGCN: two 2-layer GCN branches (H=64) + concat + FC(128->4), fp32 in/out.
// Round 9: gemm_l1 software pipeline (register double-buffer, unroll-by-2).
//   R8 post-mortem: occupancy 46%, VALU 12%, MFMA 8%, HBM 17% -- NOTHING
//   saturated, dur stuck ~135us across 3 occupancy points => per-wave
//   latency serialization (loads issue only after prev step's MFMAs).
//   Now: ping-pong buffers; step ks+1's 12 loads are issued before
//   compute(ks), so waves keep ~12 loads in flight continuously.
//   VGPR ~160 (occ ~30%) accepted: R7 proved low occ alone is not fatal.
//   Everything else unchanged from R8 (verified).
// ---------------------------------------------------------------------------

#define H 64
#define BCAP 16384            // per-bucket capacity (avg fill ~4096, +190 sigma)

static inline int ceil_div(int a, int b) { return (a + b - 1) / b; }

typedef __attribute__((ext_vector_type(8))) short short8_t;  // 8 bf16
typedef __attribute__((ext_vector_type(4))) float f32x4;

__device__ inline unsigned short f2bf_rne(float f) {
    unsigned u = __float_as_uint(f);
    u += 0x7fffu + ((u >> 16) & 1u);
    return (unsigned short)(u >> 16);
}
__device__ inline unsigned pk_bf(float a, float b) {
    return (unsigned)f2bf_rne(a) | ((unsigned)f2bf_rne(b) << 16);
}
__device__ inline float2 bf2x(unsigned w) {
    float2 r;
    r.x = __uint_as_float(w << 16);
    r.y = __uint_as_float(w & 0xffff0000u);
    return r;
}
union V8 { uint4 u4; unsigned u[4]; short8_t s; };

// RNE split-pack: (a,b) -> hi bf16x2 (packed) + lo bf16x2 (packed residual).
// Uses v_cvt_pk_bf16_f32 via __float22bfloat162_rn (same RNE as f2bf_rne).
__device__ inline void split_pack2(float a, float b, unsigned& hi, unsigned& lo) {
    union { __hip_bfloat162 h; unsigned u; } hp, lp;
    hp.h = __float22bfloat162_rn(make_float2(a, b));
    float fa = __uint_as_float(hp.u << 16);
    float fb = __uint_as_float(hp.u & 0xffff0000u);
    lp.h = __float22bfloat162_rn(make_float2(a - fa, b - fb));
    hi = hp.u;
    lo = lp.u;
}

// ---- pass 1: bucket edges by dst>>8 (packed src | dlocal<<17) -------------
// 2048 edges/block; LDS histogram; one cursor atomic per (block,bucket).
__global__ __launch_bounds__(256) void bucket_scatter_kernel(
        const int* __restrict__ src, const int* __restrict__ dst,
        int* __restrict__ cursor, unsigned* __restrict__ bucketed,
        int E, int nbkt) {
    __shared__ int lcnt[512];
    __shared__ int lbase[512];
    const int t = threadIdx.x;
    for (int b = t; b < nbkt; b += 256) lcnt[b] = 0;
    __syncthreads();

    unsigned val[8];
    int bkt[8], lpos[8];
    const int e0 = blockIdx.x * 2048;
#pragma unroll
    for (int k = 0; k < 8; ++k) {
        int e = e0 + k * 256 + t;
        bkt[k] = -1;
        if (e < E) {
            int s = src[e];
            int d = dst[e];
            int b = d >> 8;
            val[k] = (unsigned)s | ((unsigned)(d & 255) << 17);
            bkt[k] = b;
            lpos[k] = atomicAdd(&lcnt[b], 1);
        }
    }
    __syncthreads();
    for (int b = t; b < nbkt; b += 256) {
        int c = lcnt[b];
        lbase[b] = c > 0 ? atomicAdd(&cursor[b], c) : 0;
    }
    __syncthreads();
#pragma unroll
    for (int k = 0; k < 8; ++k) {
        if (bkt[k] >= 0) {
            int p = lbase[bkt[k]] + lpos[k];
            if (p < BCAP)  // impossible overflow guard (keeps writes in range)
                bucketed[(size_t)bkt[k] * BCAP + p] = val[k];
        }
    }
}

// ---- pass 2: per-bucket exact CSR + row_ptr + dinv ------------------------
// one block per bucket (256 dst nodes, ~4K edges). Dense coalesced IO.
// Block computes its own exclusive prefix over cursor[0..b) (replaces the
// standalone scan kernel: <=391 int reads + tree reduce, negligible).
__global__ __launch_bounds__(256) void bucket_csr_kernel(
        const unsigned* __restrict__ bucketed, const int* __restrict__ cursor,
        int* __restrict__ csr_src, int* __restrict__ row_ptr,
        float* __restrict__ dinv, int N, int E) {
    __shared__ int dcnt[256];
    __shared__ int dbase[256];
    __shared__ int dcur[256];
    const int t = threadIdx.x;
    const int b = blockIdx.x;

    // inline exclusive prefix: base = sum(cursor[0..b-1])
    int part = 0;
    for (int i = t; i < b; i += 256) part += cursor[i];
    dbase[t] = part;
    __syncthreads();
#pragma unroll
    for (int off = 128; off > 0; off >>= 1) {
        if (t < off) dbase[t] += dbase[t + off];
        __syncthreads();
    }
    const int base = dbase[0];
    const int cnt = min(cursor[b], BCAP);
    const unsigned* bed = bucketed + (size_t)b * BCAP;
    if (b == 0 && t == 0) row_ptr[N] = E;

    dcnt[t] = 0;
    __syncthreads();               // also fences the dbase[0] reads above
    for (int i = t; i < cnt; i += 256) {
        unsigned v = bed[i];
        atomicAdd(&dcnt[v >> 17], 1);
    }
    __syncthreads();
    int myc = dcnt[t];
    // exclusive scan over 256 (Hillis-Steele, in place)
    int acc = myc;
    dbase[t] = acc;
    __syncthreads();
#pragma unroll
    for (int off = 1; off < 256; off <<= 1) {
        int u = (t >= off) ? dbase[t - off] : 0;
        __syncthreads();
        dbase[t] += u;
        __syncthreads();
    }
    int excl = dbase[t] - myc;
    dcur[t] = excl;
    int node = b * 256 + t;
    if (node < N) {
        row_ptr[node] = base + excl;
        dinv[node] = rsqrtf((float)myc + 1.0f);  // +1 self loop
    }
    __syncthreads();
    for (int i = t; i < cnt; i += 256) {
        unsigned v = bed[i];
        int dl = v >> 17;
        int p = atomicAdd(&dcur[dl], 1);
        csr_src[base + p] = (int)(v & 0x1FFFFu);
    }
}

// ---- W fragment pre-pack, all four weights in ONE launch ------------------
// W[K][64] fp32 -> hi/lo bf16 MFMA lane order.
// Segments (exact fits): Wa K=512 -> 16 blocks, Wb K=256 -> 8, Wc/Wd K=64 -> 2+2.
// Block 0 additionally zeroes the 512-entry bucket cursor array (replaces
// the hipMemsetAsync dispatch; this kernel is enqueued before the scatter).
__global__ __launch_bounds__(256) void wfrag4_kernel(
        const float* __restrict__ Wa, uint4* __restrict__ fa,
        const float* __restrict__ Wb, uint4* __restrict__ fb,
        const float* __restrict__ Wc, uint4* __restrict__ fc,
        const float* __restrict__ Wd, uint4* __restrict__ fd,
        int* __restrict__ cursor) {
    const int bid = blockIdx.x;
    if (bid == 0) {
        cursor[threadIdx.x] = 0;
        cursor[threadIdx.x + 256] = 0;
    }
    const float* W;
    uint4* frag;
    int K, t;
    if (bid < 16)      { W = Wa; frag = fa; K = 512; t = bid * 256 + threadIdx.x; }
    else if (bid < 24) { W = Wb; frag = fb; K = 256; t = (bid - 16) * 256 + threadIdx.x; }
    else if (bid < 26) { W = Wc; frag = fc; K = 64;  t = (bid - 24) * 256 + threadIdx.x; }
    else               { W = Wd; frag = fd; K = 64;  t = (bid - 26) * 256 + threadIdx.x; }
    int total = (K >> 5) * 256;
    if (t >= total) return;
    int lane = t & 63, nt = (t >> 6) & 3, ks = t >> 8;
    int nl = lane & 15, q = lane >> 4;
    float hi[8], lo[8];
#pragma unroll
    for (int j = 0; j < 8; ++j) {
        float w = W[(size_t)(ks * 32 + q * 8 + j) * 64 + nt * 16 + nl];
        unsigned hb = f2bf_rne(w);
        float hf = __uint_as_float(((unsigned)hb) << 16);
        hi[j] = hf;
        lo[j] = w - hf;
    }
    V8 vh, vl;
#pragma unroll
    for (int j = 0; j < 4; ++j) {
        vh.u[j] = pk_bf(hi[2 * j], hi[2 * j + 1]);
        vl.u[j] = pk_bf(lo[2 * j], lo[2 * j + 1]);
    }
    size_t base = (size_t)((ks * 4 + nt) * 2) * 64 + lane;
    frag[base] = vh.u4;
    frag[base + 64] = vl.u4;
}

// ---- gemm_l1 helpers: load one K-step's operands / compute one K-step -----
__device__ inline void l1_load(const float* __restrict__ Xr0,
                               const float* __restrict__ Xr1,
                               const uint4* __restrict__ wf,
                               int ks, int q, int l,
                               float4 xf[2][2], uint4 bh[4], uint4 bl[4]) {
    xf[0][0] = *(const float4*)&Xr0[ks * 32 + q * 8];
    xf[0][1] = *(const float4*)&Xr0[ks * 32 + q * 8 + 4];
    xf[1][0] = *(const float4*)&Xr1[ks * 32 + q * 8];
    xf[1][1] = *(const float4*)&Xr1[ks * 32 + q * 8 + 4];
    const uint4* base = wf + (size_t)(ks * 8) * 64 + l;
#pragma unroll
    for (int nt = 0; nt < 4; ++nt) {
        bh[nt] = base[(size_t)(nt * 2) * 64];
        bl[nt] = base[(size_t)(nt * 2 + 1) * 64];
    }
}

__device__ inline void l1_compute(const float4 xf[2][2], const uint4 bh[4],
                                  const uint4 bl[4], f32x4 acc[2][4]) {
#pragma unroll
    for (int s = 0; s < 2; ++s) {
        float xs[8] = {xf[s][0].x, xf[s][0].y, xf[s][0].z, xf[s][0].w,
                       xf[s][1].x, xf[s][1].y, xf[s][1].z, xf[s][1].w};
        V8 ah, al;
#pragma unroll
        for (int j = 0; j < 4; ++j)
            split_pack2(xs[2 * j], xs[2 * j + 1], ah.u[j], al.u[j]);
#pragma unroll
        for (int nt = 0; nt < 4; ++nt) {
            V8 vh, vl;
            vh.u4 = bh[nt];
            vl.u4 = bl[nt];
            acc[s][nt] = __builtin_amdgcn_mfma_f32_16x16x32_bf16(ah.s, vh.s, acc[s][nt], 0, 0, 0);
            acc[s][nt] = __builtin_amdgcn_mfma_f32_16x16x32_bf16(al.s, vh.s, acc[s][nt], 0, 0, 0);
            acc[s][nt] = __builtin_amdgcn_mfma_f32_16x16x32_bf16(ah.s, vl.s, acc[s][nt], 0, 0, 0);
        }
    }
}

// ---- layer-1 GEMM, both branches in one launch, 32 rows/wave --------------
// Hout_bf16[M,64] = X_fp32[M,K] @ W (bf16x3 split). Branch by blockIdx.
// Register double-buffered ping-pong pipeline (unroll-by-2, ksteps even):
// step ks+1's 12 loads are in flight while step ks's MFMAs execute.
__global__ __launch_bounds__(256) void gemm_l1_kernel(
        const float* __restrict__ XA, const uint4* __restrict__ wfA,
        unsigned* __restrict__ HA, int KA,
        const float* __restrict__ XB, const uint4* __restrict__ wfB,
        unsigned* __restrict__ HB, int KB,
        int M, int nblkA) {
    const float* X;
    const uint4* wf;
    unsigned* Hout;
    int K, blk;
    if ((int)blockIdx.x < nblkA) { X = XA; wf = wfA; Hout = HA; K = KA; blk = blockIdx.x; }
    else                         { X = XB; wf = wfB; Hout = HB; K = KB; blk = blockIdx.x - nblkA; }

    const int tid = threadIdx.x;
    const int w = tid >> 6, l = tid & 63;
    const int m = l & 15, q = l >> 4;
    const int wbase = blk * 128 + w * 32;   // wave's 32-row region

    const float* Xr[2];
#pragma unroll
    for (int s = 0; s < 2; ++s) {
        int row = wbase + s * 16 + m;
        int rowc = row < M ? row : M - 1;
        Xr[s] = X + (size_t)rowc * K;
    }

    f32x4 acc[2][4];
#pragma unroll
    for (int s = 0; s < 2; ++s)
#pragma unroll
        for (int nt = 0; nt < 4; ++nt) acc[s][nt] = (f32x4){0.f, 0.f, 0.f, 0.f};

    const int ksteps = K >> 5;   // 16 (A) or 8 (B): always even

    float4 xfA[2][2], xfB[2][2];
    uint4 bhA[4], blA[4], bhB[4], blB[4];

    // prologue: buffer A <- ks = 0
    l1_load(Xr[0], Xr[1], wf, 0, q, l, xfA, bhA, blA);

    for (int ks = 0; ks < ksteps; ks += 2) {
        // buffer B <- ks+1 (ksteps even => ks+1 < ksteps always)
        l1_load(Xr[0], Xr[1], wf, ks + 1, q, l, xfB, bhB, blB);
        l1_compute(xfA, bhA, blA, acc);         // waits only buffer A
        if (ks + 2 < ksteps)
            l1_load(Xr[0], Xr[1], wf, ks + 2, q, l, xfA, bhA, blA);
        l1_compute(xfB, bhB, blB, acc);         // waits only buffer B
    }

#pragma unroll
    for (int s = 0; s < 2; ++s) {
        const int rbase = wbase + s * 16 + q * 4;
#pragma unroll
        for (int nt = 0; nt < 4; ++nt) {
#pragma unroll
            for (int i = 0; i < 4; ++i) {
                float f = acc[s][nt][i];
                float fo = __shfl_xor(f, 1, 64);
                int r = rbase + i;
                if (((l & 1) == 0) && r < M)
                    Hout[(size_t)r * 32 + nt * 8 + (m >> 1)] = pk_bf(f, fo);
            }
        }
    }
}

// ---- layer-2 GEMM, both branches in one launch ----------------------------
// Hout_bf16[M,64] = X_bf16[M,64] @ W (W split, 2 MFMA).
__global__ __launch_bounds__(256) void gemm_l2_kernel(
        const uint4* __restrict__ XA, const uint4* __restrict__ wfA,
        unsigned* __restrict__ HA,
        const uint4* __restrict__ XB, const uint4* __restrict__ wfB,
        unsigned* __restrict__ HB,
        int M, int nblkA) {
    const uint4* Xb;
    const uint4* wf;
    unsigned* Hout;
    int blk;
    if ((int)blockIdx.x < nblkA) { Xb = XA; wf = wfA; Hout = HA; blk = blockIdx.x; }
    else                         { Xb = XB; wf = wfB; Hout = HB; blk = blockIdx.x - nblkA; }

    const int tid = threadIdx.x;
    const int w = tid >> 6, l = tid & 63;
    const int m = l & 15, q = l >> 4;
    const int tile = blk * 64 + w * 16;
    int row = tile + m;
    int rowc = row < M ? row : M - 1;

    f32x4 acc[4];
#pragma unroll
    for (int nt = 0; nt < 4; ++nt) acc[nt] = (f32x4){0.f, 0.f, 0.f, 0.f};

#pragma unroll
    for (int ks = 0; ks < 2; ++ks) {
        V8 av;
        av.u4 = Xb[(size_t)rowc * 8 + ks * 4 + q];
        const uint4* base = wf + (size_t)(ks * 4) * 2 * 64 + l;
#pragma unroll
        for (int nt = 0; nt < 4; ++nt) {
            V8 bh, bl;
            bh.u4 = base[(size_t)(nt * 2) * 64];
            bl.u4 = base[(size_t)(nt * 2 + 1) * 64];
            acc[nt] = __builtin_amdgcn_mfma_f32_16x16x32_bf16(av.s, bh.s, acc[nt], 0, 0, 0);
            acc[nt] = __builtin_amdgcn_mfma_f32_16x16x32_bf16(av.s, bl.s, acc[nt], 0, 0, 0);
        }
    }

    const int rbase = tile + q * 4;
#pragma unroll
    for (int nt = 0; nt < 4; ++nt) {
#pragma unroll
        for (int i = 0; i < 4; ++i) {
            float f = acc[nt][i];
            float fo = __shfl_xor(f, 1, 64);
            int r = rbase + i;
            if (((l & 1) == 0) && r < M)
                Hout[(size_t)r * 32 + nt * 8 + (m >> 1)] = pk_bf(f, fo);
        }
    }
}

// ---- fused dual-branch aggregation: selfloop+gather+bias+ELU [+FC] --------
// 2 dst nodes per wave; lane l holds features (2l,2l+1) as packed bf16.
// edge norm computed from the hot dinv table (no csr_norm stream).
__global__ __launch_bounds__(256) void agg2_kernel(const unsigned* __restrict__ h1,
                                                   const unsigned* __restrict__ h2,
                                                   const float* __restrict__ dinv,
                                                   const int* __restrict__ row_ptr,
                                                   const int* __restrict__ csr_src,
                                                   const float* __restrict__ b1,
                                                   const float* __restrict__ b2,
                                                   unsigned* __restrict__ o1,
                                                   unsigned* __restrict__ o2,
                                                   const float* __restrict__ Wfc,
                                                   const float* __restrict__ bfc,
                                                   float* __restrict__ out, int n) {
    const int tid  = threadIdx.x;
    const int lane = tid & 63;
    const int wave = tid >> 6;
    const int half = lane >> 5;
    const int l    = lane & 31;
    const int hb   = half << 5;
    const int node = blockIdx.x * 8 + wave * 2 + half;
    const bool active = (node < n);

    int r0 = 0, r1 = 0;
    float di = 0.f;
    if (active) { r0 = row_ptr[node]; r1 = row_ptr[node + 1]; di = dinv[node]; }
    const float di2 = di * di;
    const int rowoff = node * 32 + l;

    float2 acc1 = make_float2(0.f, 0.f), acc2 = make_float2(0.f, 0.f);
    if (active) {
        float2 s1 = bf2x(h1[rowoff]);
        float2 s2 = bf2x(h2[rowoff]);
        acc1.x = s1.x * di2; acc1.y = s1.y * di2;
        acc2.x = s2.x * di2; acc2.y = s2.y * di2;
    }

    for (int base = r0; base < r1; base += 32) {
        int cnt = r1 - base;
        if (cnt > 32) cnt = 32;
        int j = base + (l < cnt ? l : cnt - 1);   // coalesced chunk prefetch
        int sj = csr_src[j];
        float dsj = dinv[sj];                     // hot 400 KB table
#pragma unroll 4
        for (int t = 0; t < cnt; ++t) {
            int s    = __shfl(sj, hb | t, 64);
            float nr = __shfl(dsj, hb | t, 64) * di;
            float2 g1 = bf2x(h1[s * 32 + l]);
            float2 g2 = bf2x(h2[s * 32 + l]);
            acc1.x = fmaf(g1.x, nr, acc1.x);
            acc1.y = fmaf(g1.y, nr, acc1.y);
            acc2.x = fmaf(g2.x, nr, acc2.x);
            acc2.y = fmaf(g2.y, nr, acc2.y);
        }
    }

    float2 bv1 = ((const float2*)b1)[l];
    float2 bv2 = ((const float2*)b2)[l];
    float2 v1, v2;
    v1.x = acc1.x + bv1.x; v1.y = acc1.y + bv1.y;
    v2.x = acc2.x + bv2.x; v2.y = acc2.y + bv2.y;
    v1.x = v1.x > 0.f ? v1.x : (expf(v1.x) - 1.f);
    v1.y = v1.y > 0.f ? v1.y : (expf(v1.y) - 1.f);
    v2.x = v2.x > 0.f ? v2.x : (expf(v2.x) - 1.f);
    v2.y = v2.y > 0.f ? v2.y : (expf(v2.y) - 1.f);

    if (Wfc == nullptr) {
        if (active) {
            o1[rowoff] = pk_bf(v1.x, v1.y);
            o2[rowoff] = pk_bf(v2.x, v2.y);
        }
        return;
    }

    // fused FC head
    const float* Wp1 = &Wfc[(2 * l) * 4];
    const float* Wp2 = &Wfc[(H + 2 * l) * 4];
    float a[4];
#pragma unroll
    for (int c = 0; c < 4; ++c)
        a[c] = v1.x * Wp1[c] + v1.y * Wp1[4 + c] + v2.x * Wp2[c] + v2.y * Wp2[4 + c];
#pragma unroll
    for (int off = 16; off > 0; off >>= 1) {
#pragma unroll
        for (int c = 0; c < 4; ++c)
            a[c] += __shfl_down(a[c], off, 64);
    }
    if (l == 0 && active) {
#pragma unroll
        for (int c = 0; c < 4; ++c)
            out[(size_t)node * 4 + c] = a[c] + bfc[c];
    }
}

// ---------------------------------------------------------------------------
extern "C" void kernel_launch(void* const* d_in, const int* in_sizes, int n_in,
                              void* d_out, int out_size, void* d_ws, size_t ws_size,
                              hipStream_t stream) {
    const float* x_omic1 = (const float*)d_in[0];
    const float* x_omic2 = (const float*)d_in[1];
    const int*   eidx    = (const int*)d_in[2];
    const float* W1a = (const float*)d_in[3];
    const float* b1a = (const float*)d_in[4];
    const float* W2a = (const float*)d_in[5];
    const float* b2a = (const float*)d_in[6];
    const float* W1b = (const float*)d_in[7];
    const float* b1b = (const float*)d_in[8];
    const float* W2b = (const float*)d_in[9];
    const float* b2b = (const float*)d_in[10];
    const float* Wfc = (const float*)d_in[11];
    const float* bfc = (const float*)d_in[12];
    float* out = (float*)d_out;

    const int D1 = 512, D2 = 256;
    const int N = in_sizes[0] / D1;
    const int E = in_sizes[2] / 2;
    const int* src = eidx;
    const int* dst = eidx + E;
    const int nbkt = ceil_div(N, 256);   // 391 for N=100000 (must be <= 512)

    // workspace layout (4B units, 16B-aligned chunks)
    size_t off = 0;
    auto alloc = [&](size_t elems) { size_t o = off; off += (elems + 3) & ~(size_t)3; return o; };
    float*    base_f = (float*)d_ws;
    int*      base_i = (int*)d_ws;
    unsigned* base_u = (unsigned*)d_ws;
    float*    dinv     = base_f + alloc(N);
    int*      row_ptr  = base_i + alloc(N + 1);
    int*      cursor   = base_i + alloc(512);
    unsigned* bucketed = base_u + alloc((size_t)nbkt * BCAP);
    int*      csr_src  = base_i + alloc(E);
    unsigned* h1bf     = base_u + alloc((size_t)N * 32);  // N x 64 bf16
    unsigned* h2bf     = base_u + alloc((size_t)N * 32);
    unsigned* x1bf     = base_u + alloc((size_t)N * 32);
    unsigned* x2bf     = base_u + alloc((size_t)N * 32);
    uint4*    wf1a = (uint4*)(base_u + alloc((D1 / 32) * 2 * 256 * 4));
    uint4*    wf1b = (uint4*)(base_u + alloc((D2 / 32) * 2 * 256 * 4));
    uint4*    wf2a = (uint4*)(base_u + alloc((H  / 32) * 2 * 256 * 4));
    uint4*    wf2b = (uint4*)(base_u + alloc((H  / 32) * 2 * 256 * 4));

    dim3 blk(256);
    dim3 grid_agg(ceil_div(N, 8));
    const int nblk = ceil_div(N, 64);      // gemm_l2 tiling (64 rows/block)
    const int nblkL1 = ceil_div(N, 128);   // gemm_l1 tiling (128 rows/block)

    // 1) W pre-pack (all four) + cursor zeroing — must precede the scatter.
    wfrag4_kernel<<<28, blk, 0, stream>>>(W1a, wf1a, W1b, wf1b, W2a, wf2a,
                                          W2b, wf2b, cursor);
    // 2-3) CSR build (bucketed counting sort; scan inlined into pass 3).
    bucket_scatter_kernel<<<ceil_div(E, 2048), blk, 0, stream>>>(src, dst, cursor,
                                                                 bucketed, E, nbkt);
    bucket_csr_kernel<<<nbkt, blk, 0, stream>>>(bucketed, cursor, csr_src,
                                                row_ptr, dinv, N, E);
    // 4) layer 1, both branches, one launch (128 rows/block).
    gemm_l1_kernel<<<2 * nblkL1, blk, 0, stream>>>(x_omic1, wf1a, h1bf, D1,
                                                   x_omic2, wf1b, h2bf, D2, N, nblkL1);
    // 5) layer-1 aggregation + ELU.
    agg2_kernel<<<grid_agg, blk, 0, stream>>>(h1bf, h2bf, dinv, row_ptr, csr_src,
                                              b1a, b1b, x1bf, x2bf,
                                              nullptr, nullptr, nullptr, N);
    // 6) layer 2, both branches, one launch.
    gemm_l2_kernel<<<2 * nblk, blk, 0, stream>>>((const uint4*)x1bf, wf2a, h1bf,
                                                 (const uint4*)x2bf, wf2b, h2bf,
                                                 N, nblk);
    // 7) layer-2 aggregation + ELU + fused FC head.
    agg2_kernel<<<grid_agg, blk, 0, stream>>>(h1bf, h2bf, dinv, row_ptr, csr_src,
                                              b2a, b2b, nullptr, nullptr,
                                              Wfc, bfc, out, N);
}

// Round 5
// 675.156 us; speedup vs baseline: 1.0203x; 1.0095x over previous
//
#include <hip/hip_runtime.h>
#include <hip/hip_bf16.h>
#include <math.h>

// ---------------------------------------------------------------------------
// MoGCN: two 2-layer GCN branches (H=64) + concat + FC(128->4), fp32 in/out.
// Round 10: gemm_l1 rebuilt as LDS double-buffered 2-phase pipeline with
// global_load_lds (T3 minimum recipe).
//   R9 post-mortem: register ping-pong was COLLAPSED by the compiler
//   (VGPR=76 proves both buffers never coexisted); dur stuck ~127us =
//   serial load-latency chain. global_load_lds cannot be sunk by the
//   compiler; the stage(k+1) || compute(k) overlap is structural.
//   X-tile [128 rows][32 K] fp32 (16KB) + wf tile (8KB), both x2 buffers
//   = 48KB LDS, 3 blocks/CU. X LDS layout XOR-swizzled (slot ^= row&7,
//   16B slots) on BOTH the pre-swizzled global source and the ds_read
//   (rule 21) -> 2-way max bank conflict.
//   Everything else unchanged from R9 (verified).
// ---------------------------------------------------------------------------

#define H 64
#define BCAP 16384            // per-bucket capacity (avg fill ~4096, +190 sigma)

static inline int ceil_div(int a, int b) { return (a + b - 1) / b; }

typedef __attribute__((ext_vector_type(8))) short short8_t;  // 8 bf16
typedef __attribute__((ext_vector_type(4))) float f32x4;

__device__ inline unsigned short f2bf_rne(float f) {
    unsigned u = __float_as_uint(f);
    u += 0x7fffu + ((u >> 16) & 1u);
    return (unsigned short)(u >> 16);
}
__device__ inline unsigned pk_bf(float a, float b) {
    return (unsigned)f2bf_rne(a) | ((unsigned)f2bf_rne(b) << 16);
}
__device__ inline float2 bf2x(unsigned w) {
    float2 r;
    r.x = __uint_as_float(w << 16);
    r.y = __uint_as_float(w & 0xffff0000u);
    return r;
}
union V8 { uint4 u4; unsigned u[4]; short8_t s; };

// RNE split-pack: (a,b) -> hi bf16x2 (packed) + lo bf16x2 (packed residual).
// Uses v_cvt_pk_bf16_f32 via __float22bfloat162_rn (same RNE as f2bf_rne).
__device__ inline void split_pack2(float a, float b, unsigned& hi, unsigned& lo) {
    union { __hip_bfloat162 h; unsigned u; } hp, lp;
    hp.h = __float22bfloat162_rn(make_float2(a, b));
    float fa = __uint_as_float(hp.u << 16);
    float fb = __uint_as_float(hp.u & 0xffff0000u);
    lp.h = __float22bfloat162_rn(make_float2(a - fa, b - fb));
    hi = hp.u;
    lo = lp.u;
}

// async global -> LDS, 16B per lane; lds dest must be wave-uniform base
// (HW writes lane i at base + i*16); global src is per-lane.
__device__ inline void async16(void* lds, const void* g) {
    __builtin_amdgcn_global_load_lds(
        (const __attribute__((address_space(1))) unsigned*)g,
        (__attribute__((address_space(3))) unsigned*)lds,
        16, 0, 0);
}

// ---- pass 1: bucket edges by dst>>8 (packed src | dlocal<<17) -------------
// 2048 edges/block; LDS histogram; one cursor atomic per (block,bucket).
__global__ __launch_bounds__(256) void bucket_scatter_kernel(
        const int* __restrict__ src, const int* __restrict__ dst,
        int* __restrict__ cursor, unsigned* __restrict__ bucketed,
        int E, int nbkt) {
    __shared__ int lcnt[512];
    __shared__ int lbase[512];
    const int t = threadIdx.x;
    for (int b = t; b < nbkt; b += 256) lcnt[b] = 0;
    __syncthreads();

    unsigned val[8];
    int bkt[8], lpos[8];
    const int e0 = blockIdx.x * 2048;
#pragma unroll
    for (int k = 0; k < 8; ++k) {
        int e = e0 + k * 256 + t;
        bkt[k] = -1;
        if (e < E) {
            int s = src[e];
            int d = dst[e];
            int b = d >> 8;
            val[k] = (unsigned)s | ((unsigned)(d & 255) << 17);
            bkt[k] = b;
            lpos[k] = atomicAdd(&lcnt[b], 1);
        }
    }
    __syncthreads();
    for (int b = t; b < nbkt; b += 256) {
        int c = lcnt[b];
        lbase[b] = c > 0 ? atomicAdd(&cursor[b], c) : 0;
    }
    __syncthreads();
#pragma unroll
    for (int k = 0; k < 8; ++k) {
        if (bkt[k] >= 0) {
            int p = lbase[bkt[k]] + lpos[k];
            if (p < BCAP)  // impossible overflow guard (keeps writes in range)
                bucketed[(size_t)bkt[k] * BCAP + p] = val[k];
        }
    }
}

// ---- pass 2: per-bucket exact CSR + row_ptr + dinv ------------------------
// one block per bucket (256 dst nodes, ~4K edges). Dense coalesced IO.
// Block computes its own exclusive prefix over cursor[0..b) (replaces the
// standalone scan kernel: <=391 int reads + tree reduce, negligible).
__global__ __launch_bounds__(256) void bucket_csr_kernel(
        const unsigned* __restrict__ bucketed, const int* __restrict__ cursor,
        int* __restrict__ csr_src, int* __restrict__ row_ptr,
        float* __restrict__ dinv, int N, int E) {
    __shared__ int dcnt[256];
    __shared__ int dbase[256];
    __shared__ int dcur[256];
    const int t = threadIdx.x;
    const int b = blockIdx.x;

    // inline exclusive prefix: base = sum(cursor[0..b-1])
    int part = 0;
    for (int i = t; i < b; i += 256) part += cursor[i];
    dbase[t] = part;
    __syncthreads();
#pragma unroll
    for (int off = 128; off > 0; off >>= 1) {
        if (t < off) dbase[t] += dbase[t + off];
        __syncthreads();
    }
    const int base = dbase[0];
    const int cnt = min(cursor[b], BCAP);
    const unsigned* bed = bucketed + (size_t)b * BCAP;
    if (b == 0 && t == 0) row_ptr[N] = E;

    dcnt[t] = 0;
    __syncthreads();               // also fences the dbase[0] reads above
    for (int i = t; i < cnt; i += 256) {
        unsigned v = bed[i];
        atomicAdd(&dcnt[v >> 17], 1);
    }
    __syncthreads();
    int myc = dcnt[t];
    // exclusive scan over 256 (Hillis-Steele, in place)
    int acc = myc;
    dbase[t] = acc;
    __syncthreads();
#pragma unroll
    for (int off = 1; off < 256; off <<= 1) {
        int u = (t >= off) ? dbase[t - off] : 0;
        __syncthreads();
        dbase[t] += u;
        __syncthreads();
    }
    int excl = dbase[t] - myc;
    dcur[t] = excl;
    int node = b * 256 + t;
    if (node < N) {
        row_ptr[node] = base + excl;
        dinv[node] = rsqrtf((float)myc + 1.0f);  // +1 self loop
    }
    __syncthreads();
    for (int i = t; i < cnt; i += 256) {
        unsigned v = bed[i];
        int dl = v >> 17;
        int p = atomicAdd(&dcur[dl], 1);
        csr_src[base + p] = (int)(v & 0x1FFFFu);
    }
}

// ---- W fragment pre-pack, all four weights in ONE launch ------------------
// W[K][64] fp32 -> hi/lo bf16 MFMA lane order.
// Segments (exact fits): Wa K=512 -> 16 blocks, Wb K=256 -> 8, Wc/Wd K=64 -> 2+2.
// Block 0 additionally zeroes the 512-entry bucket cursor array (replaces
// the hipMemsetAsync dispatch; this kernel is enqueued before the scatter).
__global__ __launch_bounds__(256) void wfrag4_kernel(
        const float* __restrict__ Wa, uint4* __restrict__ fa,
        const float* __restrict__ Wb, uint4* __restrict__ fb,
        const float* __restrict__ Wc, uint4* __restrict__ fc,
        const float* __restrict__ Wd, uint4* __restrict__ fd,
        int* __restrict__ cursor) {
    const int bid = blockIdx.x;
    if (bid == 0) {
        cursor[threadIdx.x] = 0;
        cursor[threadIdx.x + 256] = 0;
    }
    const float* W;
    uint4* frag;
    int K, t;
    if (bid < 16)      { W = Wa; frag = fa; K = 512; t = bid * 256 + threadIdx.x; }
    else if (bid < 24) { W = Wb; frag = fb; K = 256; t = (bid - 16) * 256 + threadIdx.x; }
    else if (bid < 26) { W = Wc; frag = fc; K = 64;  t = (bid - 24) * 256 + threadIdx.x; }
    else               { W = Wd; frag = fd; K = 64;  t = (bid - 26) * 256 + threadIdx.x; }
    int total = (K >> 5) * 256;
    if (t >= total) return;
    int lane = t & 63, nt = (t >> 6) & 3, ks = t >> 8;
    int nl = lane & 15, q = lane >> 4;
    float hi[8], lo[8];
#pragma unroll
    for (int j = 0; j < 8; ++j) {
        float w = W[(size_t)(ks * 32 + q * 8 + j) * 64 + nt * 16 + nl];
        unsigned hb = f2bf_rne(w);
        float hf = __uint_as_float(((unsigned)hb) << 16);
        hi[j] = hf;
        lo[j] = w - hf;
    }
    V8 vh, vl;
#pragma unroll
    for (int j = 0; j < 4; ++j) {
        vh.u[j] = pk_bf(hi[2 * j], hi[2 * j + 1]);
        vl.u[j] = pk_bf(lo[2 * j], lo[2 * j + 1]);
    }
    size_t base = (size_t)((ks * 4 + nt) * 2) * 64 + lane;
    frag[base] = vh.u4;
    frag[base + 64] = vl.u4;
}

// ---- layer-1 GEMM: LDS double-buffered 2-phase pipeline -------------------
// Hout_bf16[M,64] = X_fp32[M,K] @ W (bf16x3 split). Branch by blockIdx.
// 128 rows/block, 4 waves, 32 rows/wave (2x 16-row subtiles).
// Per K-step: stage X-tile (16KB, XOR-swizzled) + wf-tile (8KB, linear)
// for step ks+1 via global_load_lds, then compute step ks from LDS.
// __syncthreads() drains vmcnt(0) -> next buffer ready (T3 minimum).
__global__ __launch_bounds__(256) void gemm_l1_kernel(
        const float* __restrict__ XA, const uint4* __restrict__ wfA,
        unsigned* __restrict__ HA, int KA,
        const float* __restrict__ XB, const uint4* __restrict__ wfB,
        unsigned* __restrict__ HB, int KB,
        int M, int nblkA) {
    __shared__ __align__(16) unsigned xlds[2][4096];   // 2 x 16 KB: [row 0..127][slot 0..7] 16B chunks
    __shared__ __align__(16) unsigned flds[2][2048];   // 2 x  8 KB: [nt*2+h][lane] 16B chunks

    const float* X;
    const uint4* wf;
    unsigned* Hout;
    int K, blk;
    if ((int)blockIdx.x < nblkA) { X = XA; wf = wfA; Hout = HA; K = KA; blk = blockIdx.x; }
    else                         { X = XB; wf = wfB; Hout = HB; K = KB; blk = blockIdx.x - nblkA; }

    const int tid = threadIdx.x;
    const int w = tid >> 6, l = tid & 63;
    const int m = l & 15, q = l >> 4;
    const int row0 = blk * 128;
    const int ksteps = K >> 5;
    const unsigned* wfu = (const unsigned*)wf;

    // precompute per-lane X staging source (row, swizzled slot) for 4 chunks
    // chunk c = w*256 + j*64 + l ; r = c>>3 ; s_lds = c&7 ; s_glob = s_lds^(r&7)
    const float* xsrc[4];
    int xdst[4];
#pragma unroll
    for (int j = 0; j < 4; ++j) {
        int c = w * 256 + j * 64 + l;
        int r = c >> 3;
        int sg = (c & 7) ^ (r & 7);
        int row = row0 + r;
        row = row < M ? row : M - 1;
        xsrc[j] = X + (size_t)row * K + sg * 4;     // + ks*32 at issue time
        xdst[j] = (w * 256 + j * 64) * 4;           // uniform word offset
    }

    f32x4 acc[2][4];
#pragma unroll
    for (int s = 0; s < 2; ++s)
#pragma unroll
        for (int nt = 0; nt < 4; ++nt) acc[s][nt] = (f32x4){0.f, 0.f, 0.f, 0.f};

    // ---- stage(buffer b, K-step ks): 6 global_load_lds per wave ----
    auto stage = [&](int b, int ks) {
#pragma unroll
        for (int j = 0; j < 4; ++j)
            async16(&xlds[b][xdst[j]], xsrc[j] + ks * 32);
#pragma unroll
        for (int j = 0; j < 2; ++j) {
            int c0 = w * 128 + j * 64;              // uniform chunk base
            async16(&flds[b][c0 * 4], wfu + ((size_t)ks * 512 + c0 + l) * 4);
        }
    };

    // ---- compute(buffer b): 12 ds_read_b128 + pack + 24 MFMA ----
    auto compute = [&](int b) {
        uint4 bh[4], bl[4];
#pragma unroll
        for (int nt = 0; nt < 4; ++nt) {
            bh[nt] = *(const uint4*)&flds[b][((nt * 2) * 64 + l) * 4];
            bl[nt] = *(const uint4*)&flds[b][((nt * 2 + 1) * 64 + l) * 4];
        }
#pragma unroll
        for (int s = 0; s < 2; ++s) {
            int r = w * 32 + s * 16 + m;
            int sw = r & 7;
            float4 x0 = *(const float4*)&xlds[b][(r * 8 + ((2 * q) ^ sw)) * 4];
            float4 x1 = *(const float4*)&xlds[b][(r * 8 + ((2 * q + 1) ^ sw)) * 4];
            float xs[8] = {x0.x, x0.y, x0.z, x0.w, x1.x, x1.y, x1.z, x1.w};
            V8 ah, al;
#pragma unroll
            for (int j = 0; j < 4; ++j)
                split_pack2(xs[2 * j], xs[2 * j + 1], ah.u[j], al.u[j]);
#pragma unroll
            for (int nt = 0; nt < 4; ++nt) {
                V8 vh, vl;
                vh.u4 = bh[nt];
                vl.u4 = bl[nt];
                acc[s][nt] = __builtin_amdgcn_mfma_f32_16x16x32_bf16(ah.s, vh.s, acc[s][nt], 0, 0, 0);
                acc[s][nt] = __builtin_amdgcn_mfma_f32_16x16x32_bf16(al.s, vh.s, acc[s][nt], 0, 0, 0);
                acc[s][nt] = __builtin_amdgcn_mfma_f32_16x16x32_bf16(ah.s, vl.s, acc[s][nt], 0, 0, 0);
            }
        }
    };

    // ---- 2-phase pipeline ----
    stage(0, 0);
    __syncthreads();                  // drains vmcnt(0) before barrier
    int buf = 0;
    for (int ks = 0; ks + 1 < ksteps; ++ks) {
        stage(buf ^ 1, ks + 1);       // in flight across compute(buf)
        compute(buf);
        __syncthreads();
        buf ^= 1;
    }
    compute(buf);

    // ---- epilogue store ----
#pragma unroll
    for (int s = 0; s < 2; ++s) {
        const int rbase = row0 + w * 32 + s * 16 + q * 4;
#pragma unroll
        for (int nt = 0; nt < 4; ++nt) {
#pragma unroll
            for (int i = 0; i < 4; ++i) {
                float f = acc[s][nt][i];
                float fo = __shfl_xor(f, 1, 64);
                int r = rbase + i;
                if (((l & 1) == 0) && r < M)
                    Hout[(size_t)r * 32 + nt * 8 + (m >> 1)] = pk_bf(f, fo);
            }
        }
    }
}

// ---- layer-2 GEMM, both branches in one launch ----------------------------
// Hout_bf16[M,64] = X_bf16[M,64] @ W (W split, 2 MFMA).
__global__ __launch_bounds__(256) void gemm_l2_kernel(
        const uint4* __restrict__ XA, const uint4* __restrict__ wfA,
        unsigned* __restrict__ HA,
        const uint4* __restrict__ XB, const uint4* __restrict__ wfB,
        unsigned* __restrict__ HB,
        int M, int nblkA) {
    const uint4* Xb;
    const uint4* wf;
    unsigned* Hout;
    int blk;
    if ((int)blockIdx.x < nblkA) { Xb = XA; wf = wfA; Hout = HA; blk = blockIdx.x; }
    else                         { Xb = XB; wf = wfB; Hout = HB; blk = blockIdx.x - nblkA; }

    const int tid = threadIdx.x;
    const int w = tid >> 6, l = tid & 63;
    const int m = l & 15, q = l >> 4;
    const int tile = blk * 64 + w * 16;
    int row = tile + m;
    int rowc = row < M ? row : M - 1;

    f32x4 acc[4];
#pragma unroll
    for (int nt = 0; nt < 4; ++nt) acc[nt] = (f32x4){0.f, 0.f, 0.f, 0.f};

#pragma unroll
    for (int ks = 0; ks < 2; ++ks) {
        V8 av;
        av.u4 = Xb[(size_t)rowc * 8 + ks * 4 + q];
        const uint4* base = wf + (size_t)(ks * 4) * 2 * 64 + l;
#pragma unroll
        for (int nt = 0; nt < 4; ++nt) {
            V8 bh, bl;
            bh.u4 = base[(size_t)(nt * 2) * 64];
            bl.u4 = base[(size_t)(nt * 2 + 1) * 64];
            acc[nt] = __builtin_amdgcn_mfma_f32_16x16x32_bf16(av.s, bh.s, acc[nt], 0, 0, 0);
            acc[nt] = __builtin_amdgcn_mfma_f32_16x16x32_bf16(av.s, bl.s, acc[nt], 0, 0, 0);
        }
    }

    const int rbase = tile + q * 4;
#pragma unroll
    for (int nt = 0; nt < 4; ++nt) {
#pragma unroll
        for (int i = 0; i < 4; ++i) {
            float f = acc[nt][i];
            float fo = __shfl_xor(f, 1, 64);
            int r = rbase + i;
            if (((l & 1) == 0) && r < M)
                Hout[(size_t)r * 32 + nt * 8 + (m >> 1)] = pk_bf(f, fo);
        }
    }
}

// ---- fused dual-branch aggregation: selfloop+gather+bias+ELU [+FC] --------
// 2 dst nodes per wave; lane l holds features (2l,2l+1) as packed bf16.
// edge norm computed from the hot dinv table (no csr_norm stream).
__global__ __launch_bounds__(256) void agg2_kernel(const unsigned* __restrict__ h1,
                                                   const unsigned* __restrict__ h2,
                                                   const float* __restrict__ dinv,
                                                   const int* __restrict__ row_ptr,
                                                   const int* __restrict__ csr_src,
                                                   const float* __restrict__ b1,
                                                   const float* __restrict__ b2,
                                                   unsigned* __restrict__ o1,
                                                   unsigned* __restrict__ o2,
                                                   const float* __restrict__ Wfc,
                                                   const float* __restrict__ bfc,
                                                   float* __restrict__ out, int n) {
    const int tid  = threadIdx.x;
    const int lane = tid & 63;
    const int wave = tid >> 6;
    const int half = lane >> 5;
    const int l    = lane & 31;
    const int hb   = half << 5;
    const int node = blockIdx.x * 8 + wave * 2 + half;
    const bool active = (node < n);

    int r0 = 0, r1 = 0;
    float di = 0.f;
    if (active) { r0 = row_ptr[node]; r1 = row_ptr[node + 1]; di = dinv[node]; }
    const float di2 = di * di;
    const int rowoff = node * 32 + l;

    float2 acc1 = make_float2(0.f, 0.f), acc2 = make_float2(0.f, 0.f);
    if (active) {
        float2 s1 = bf2x(h1[rowoff]);
        float2 s2 = bf2x(h2[rowoff]);
        acc1.x = s1.x * di2; acc1.y = s1.y * di2;
        acc2.x = s2.x * di2; acc2.y = s2.y * di2;
    }

    for (int base = r0; base < r1; base += 32) {
        int cnt = r1 - base;
        if (cnt > 32) cnt = 32;
        int j = base + (l < cnt ? l : cnt - 1);   // coalesced chunk prefetch
        int sj = csr_src[j];
        float dsj = dinv[sj];                     // hot 400 KB table
#pragma unroll 4
        for (int t = 0; t < cnt; ++t) {
            int s    = __shfl(sj, hb | t, 64);
            float nr = __shfl(dsj, hb | t, 64) * di;
            float2 g1 = bf2x(h1[s * 32 + l]);
            float2 g2 = bf2x(h2[s * 32 + l]);
            acc1.x = fmaf(g1.x, nr, acc1.x);
            acc1.y = fmaf(g1.y, nr, acc1.y);
            acc2.x = fmaf(g2.x, nr, acc2.x);
            acc2.y = fmaf(g2.y, nr, acc2.y);
        }
    }

    float2 bv1 = ((const float2*)b1)[l];
    float2 bv2 = ((const float2*)b2)[l];
    float2 v1, v2;
    v1.x = acc1.x + bv1.x; v1.y = acc1.y + bv1.y;
    v2.x = acc2.x + bv2.x; v2.y = acc2.y + bv2.y;
    v1.x = v1.x > 0.f ? v1.x : (expf(v1.x) - 1.f);
    v1.y = v1.y > 0.f ? v1.y : (expf(v1.y) - 1.f);
    v2.x = v2.x > 0.f ? v2.x : (expf(v2.x) - 1.f);
    v2.y = v2.y > 0.f ? v2.y : (expf(v2.y) - 1.f);

    if (Wfc == nullptr) {
        if (active) {
            o1[rowoff] = pk_bf(v1.x, v1.y);
            o2[rowoff] = pk_bf(v2.x, v2.y);
        }
        return;
    }

    // fused FC head
    const float* Wp1 = &Wfc[(2 * l) * 4];
    const float* Wp2 = &Wfc[(H + 2 * l) * 4];
    float a[4];
#pragma unroll
    for (int c = 0; c < 4; ++c)
        a[c] = v1.x * Wp1[c] + v1.y * Wp1[4 + c] + v2.x * Wp2[c] + v2.y * Wp2[4 + c];
#pragma unroll
    for (int off = 16; off > 0; off >>= 1) {
#pragma unroll
        for (int c = 0; c < 4; ++c)
            a[c] += __shfl_down(a[c], off, 64);
    }
    if (l == 0 && active) {
#pragma unroll
        for (int c = 0; c < 4; ++c)
            out[(size_t)node * 4 + c] = a[c] + bfc[c];
    }
}

// ---------------------------------------------------------------------------
extern "C" void kernel_launch(void* const* d_in, const int* in_sizes, int n_in,
                              void* d_out, int out_size, void* d_ws, size_t ws_size,
                              hipStream_t stream) {
    const float* x_omic1 = (const float*)d_in[0];
    const float* x_omic2 = (const float*)d_in[1];
    const int*   eidx    = (const int*)d_in[2];
    const float* W1a = (const float*)d_in[3];
    const float* b1a = (const float*)d_in[4];
    const float* W2a = (const float*)d_in[5];
    const float* b2a = (const float*)d_in[6];
    const float* W1b = (const float*)d_in[7];
    const float* b1b = (const float*)d_in[8];
    const float* W2b = (const float*)d_in[9];
    const float* b2b = (const float*)d_in[10];
    const float* Wfc = (const float*)d_in[11];
    const float* bfc = (const float*)d_in[12];
    float* out = (float*)d_out;

    const int D1 = 512, D2 = 256;
    const int N = in_sizes[0] / D1;
    const int E = in_sizes[2] / 2;
    const int* src = eidx;
    const int* dst = eidx + E;
    const int nbkt = ceil_div(N, 256);   // 391 for N=100000 (must be <= 512)

    // workspace layout (4B units, 16B-aligned chunks)
    size_t off = 0;
    auto alloc = [&](size_t elems) { size_t o = off; off += (elems + 3) & ~(size_t)3; return o; };
    float*    base_f = (float*)d_ws;
    int*      base_i = (int*)d_ws;
    unsigned* base_u = (unsigned*)d_ws;
    float*    dinv     = base_f + alloc(N);
    int*      row_ptr  = base_i + alloc(N + 1);
    int*      cursor   = base_i + alloc(512);
    unsigned* bucketed = base_u + alloc((size_t)nbkt * BCAP);
    int*      csr_src  = base_i + alloc(E);
    unsigned* h1bf     = base_u + alloc((size_t)N * 32);  // N x 64 bf16
    unsigned* h2bf     = base_u + alloc((size_t)N * 32);
    unsigned* x1bf     = base_u + alloc((size_t)N * 32);
    unsigned* x2bf     = base_u + alloc((size_t)N * 32);
    uint4*    wf1a = (uint4*)(base_u + alloc((D1 / 32) * 2 * 256 * 4));
    uint4*    wf1b = (uint4*)(base_u + alloc((D2 / 32) * 2 * 256 * 4));
    uint4*    wf2a = (uint4*)(base_u + alloc((H  / 32) * 2 * 256 * 4));
    uint4*    wf2b = (uint4*)(base_u + alloc((H  / 32) * 2 * 256 * 4));

    dim3 blk(256);
    dim3 grid_agg(ceil_div(N, 8));
    const int nblk = ceil_div(N, 64);      // gemm_l2 tiling (64 rows/block)
    const int nblkL1 = ceil_div(N, 128);   // gemm_l1 tiling (128 rows/block)

    // 1) W pre-pack (all four) + cursor zeroing — must precede the scatter.
    wfrag4_kernel<<<28, blk, 0, stream>>>(W1a, wf1a, W1b, wf1b, W2a, wf2a,
                                          W2b, wf2b, cursor);
    // 2-3) CSR build (bucketed counting sort; scan inlined into pass 3).
    bucket_scatter_kernel<<<ceil_div(E, 2048), blk, 0, stream>>>(src, dst, cursor,
                                                                 bucketed, E, nbkt);
    bucket_csr_kernel<<<nbkt, blk, 0, stream>>>(bucketed, cursor, csr_src,
                                                row_ptr, dinv, N, E);
    // 4) layer 1, both branches, one launch (128 rows/block).
    gemm_l1_kernel<<<2 * nblkL1, blk, 0, stream>>>(x_omic1, wf1a, h1bf, D1,
                                                   x_omic2, wf1b, h2bf, D2, N, nblkL1);
    // 5) layer-1 aggregation + ELU.
    agg2_kernel<<<grid_agg, blk, 0, stream>>>(h1bf, h2bf, dinv, row_ptr, csr_src,
                                              b1a, b1b, x1bf, x2bf,
                                              nullptr, nullptr, nullptr, N);
    // 6) layer 2, both branches, one launch.
    gemm_l2_kernel<<<2 * nblk, blk, 0, stream>>>((const uint4*)x1bf, wf2a, h1bf,
                                                 (const uint4*)x2bf, wf2b, h2bf,
                                                 N, nblk);
    // 7) layer-2 aggregation + ELU + fused FC head.
    agg2_kernel<<<grid_agg, blk, 0, stream>>>(h1bf, h2bf, dinv, row_ptr, csr_src,
                                              b2a, b2b, nullptr, nullptr,
                                              Wfc, bfc, out, N);
}